// Round 6
// baseline (189449.158 us; speedup 1.0000x reference)
//
#include <hip/hip_runtime.h>
#include <hip/hip_fp16.h>

// ============================================================================
// LSTM_78176994722094: 2-layer LSTM (B=128, D_IN=128, T=1024, H=512) + fc head.
//
// Round 6 = Round 5 (XCD-local clusters) with the deadlock fixed.
// R5 hang diagnosis: local-mode flag publish was a VOLATILE store -> lowers
// with sc0+sc1 -> writes AROUND the XCD-local L2 to the MALL. Pollers use
// sc0-only loads -> hit the local L2's stale clean copy of the flag line ->
// spin forever (MALL never probes XCD L2s). Fixes:
//   1. Local flag publish = plain store (WORKGROUP-scope atomic store emits
//      global_store_dword with NO sc bits) -> write-through L1 updates the
//      local L2 line -> sc0 pollers see it. Same coherence class as the data
//      stores (plain stores + sc0 loads meet at the XCD L2).
//   2. Tight spin guards: local 2048 polls (~0.2s worst-case total run),
//      fallback 1<<15. A residual coherence failure now finishes fast with a
//      diagnostic absmax instead of hanging the harness.
//   3. h0 published right after its gate math (overlaps L1h MFMA chain).
//
// Design: persistent kernel, 8 clusters x 32 WGs (256 blocks, 1/CU, 4 waves).
// Startup: blocks read HW_REG_XCC_ID, claim slots via agent atomics; last
// arriver publishes mode. Balanced (32/XCD) -> LOCAL mode: cluster = XCD,
// all per-round traffic (h exchange, flags, x window) through the XCD-local
// L2 (sc0 loads + plain stores, ~200cy RTT). Unbalanced -> R4 MALL fallback
// (proven @ 6666us). Cluster c owns batch rows [16c,16c+16). Each wave holds
// 16 rows of each matrix as MFMA A-fragments in VGPRs, split-precision
// (hi fp16 + 2^-11*lo fp16 on Whh0/Wih1/Wih0; absmax 1.22e-4). Layer 1 skewed
// one step behind layer 0 -> ONE flag barrier per round:
//   round r: compute h0[r] (L0) and h1[r-1] (L1) from h0[r-1], h1[r-2].
//
// Workspace (<4MB):
//   [0, 2KB)           flags: u32 per (cluster,wg), 64-u32 stride per cluster
//   [4KB, 4.5KB)       claim[8] / mode / arrive (startup handshake)
//   [64KB, 576KB)      h exchange: [parity2][cluster8][layer2][b16][ch512] fp16
//   [640KB, 640KB+3MB) xTw: [slot3][cluster8][tau32][b16][d128] fp16
// ============================================================================

typedef _Float16 half8 __attribute__((ext_vector_type(8)));
typedef float f32x4 __attribute__((ext_vector_type(4)));
typedef unsigned long long u64;
typedef u64 u64x2 __attribute__((ext_vector_type(2)));
typedef unsigned int u32x4 __attribute__((ext_vector_type(4)));

#define MFMA16(a, b, c) __builtin_amdgcn_mfma_f32_16x16x32_f16((a), (b), (c), 0, 0, 0)

#define WS_EXCH_OFF (64 << 10)
#define WS_XTW_OFF (640 << 10)
// sync word indices (u32) within ws base
#define SYNC_FLAGS 0      // 8 clusters x 64 u32
#define SYNC_CLAIM 1024   // 8 u32
#define SYNC_MODE 1040    // 1 u32 (0=undecided, 1=fallback, 2=local)
#define SYNC_ARRIVE 1056  // 1 u32

__device__ __forceinline__ float sigf(float x) {
  return __builtin_amdgcn_rcpf(1.f + exp2f(-1.44269504f * x));
}
__device__ __forceinline__ float tanhf_(float x) {
  return 1.f - 2.f * __builtin_amdgcn_rcpf(1.f + exp2f(2.88539008f * x));
}
__device__ __forceinline__ unsigned short f2h(float x) {
  _Float16 h = (_Float16)x;  // RNE
  unsigned short b;
  __builtin_memcpy(&b, &h, 2);
  return b;
}

// sc0-only loads: bypass L1, served by the XCD-shared L2 (the intra-XCD
// coherence point for plain write-through stores). LOCAL mode only.
__device__ __forceinline__ u32x4 ld128_sc0(const void* p) {
  u32x4 d;
  asm volatile("global_load_dwordx4 %0, %1, off sc0" : "=v"(d) : "v"(p));
  return d;
}
__device__ __forceinline__ unsigned ld32_sc0_wait(const void* p) {
  unsigned d;
  asm volatile("global_load_dword %0, %1, off sc0\n\ts_waitcnt vmcnt(0)"
               : "=v"(d)
               : "v"(p)
               : "memory");
  return d;
}
__device__ __forceinline__ void waitv0() {
  asm volatile("s_waitcnt vmcnt(0)" ::: "memory");
}

// split 8 fp32 weights -> hi fp16 + lo fp16 (lo = (w - hi) * 2^11)
__device__ __forceinline__ void cvt_split(const f32x4& a, const f32x4& b,
                                          half8& hi, half8& lo) {
#pragma unroll
  for (int i = 0; i < 4; ++i) {
    float w0 = a[i], w1 = b[i];
    _Float16 h0 = (_Float16)w0, h1 = (_Float16)w1;
    hi[i] = h0;
    hi[i + 4] = h1;
    lo[i] = (_Float16)((w0 - (float)h0) * 2048.0f);
    lo[i + 4] = (_Float16)((w1 - (float)h1) * 2048.0f);
  }
}
// scale a fragment by 2^-11 (exact exponent shift; v_pk_mul_f16)
__device__ __forceinline__ half8 hscale(half8 v) {
  half8 r;
#pragma unroll
  for (int i = 0; i < 8; ++i) r[i] = v[i] * (_Float16)4.8828125e-4f;
  return r;
}

// ---------------------------------------------------------------------------
// Prepass: fill xTw window 0 (t=0..31) slot 0, zero sync area (16KB) and out.
// Kernel-end writeback makes these stores visible device-wide to the scan.
// ---------------------------------------------------------------------------
__global__ void __launch_bounds__(256) prep_kernel(const float* __restrict__ x,
                                                   _Float16* __restrict__ xTw,
                                                   unsigned* __restrict__ sync,
                                                   float* __restrict__ out) {
  const int bid = blockIdx.x;  // 128 = 8c * 16b
  const int c = bid >> 4, b16 = bid & 15;
  const int tid = threadIdx.x;
  if (bid == 0) {
#pragma unroll
    for (int i = 0; i < 16; ++i) sync[i * 256 + tid] = 0;  // 16KB sync area
    out[tid] = 0.f;  // out_size = B*OUT = 256
  }
  const int d = tid & 127, th = tid >> 7;  // th: tau half (0/1)
  const float* src = x + ((size_t)(c * 16 + b16) * 128 + d) * 1024 + th * 16;
  _Float16* dst = xTw + ((size_t)c * 32 + th * 16) * (16 * 128) + b16 * 128 + d;
#pragma unroll
  for (int i = 0; i < 16; ++i) dst[(size_t)i * (16 * 128)] = (_Float16)src[i];
}

// ---------------------------------------------------------------------------
// Persistent scan kernel. MFMA 16x16x32 f16 layouts (verified R1-R4):
//   A[m=lane&15][k=(lane>>4)*8+j], B[k][n=lane&15], D[m=(lane>>4)*4+reg][n].
// ---------------------------------------------------------------------------
__global__ void __launch_bounds__(256, 1) lstm_scan(
    const float* __restrict__ Whh0, const float* __restrict__ bih0,
    const float* __restrict__ bhh0, const float* __restrict__ Wih1,
    const float* __restrict__ Whh1, const float* __restrict__ bih1,
    const float* __restrict__ bhh1, const float* __restrict__ fcW,
    const float* __restrict__ fcb, const float* __restrict__ Wih0,
    const float* __restrict__ x, unsigned* __restrict__ sync,
    unsigned short* __restrict__ exch, _Float16* __restrict__ xTw,
    float* __restrict__ out) {
  __shared__ __align__(16) char ldsbuf[33280 + 1024];
  _Float16(*hbuf)[16][520] = (_Float16(*)[16][520])ldsbuf;  // [2][16][520]
  unsigned short(*hout)[16][16] = (unsigned short(*)[16][16])(ldsbuf + 33280);
  __shared__ unsigned s_bcast[2];

  const int tid = threadIdx.x;
  const int wave = tid >> 6;
  const int lane = tid & 63;
  const int q = lane >> 4;
  const int bb = lane & 15;

  // ---- startup: XCD discovery + slot claim + grid barrier + mode decide ----
  unsigned xcc;
  asm("s_getreg_b32 %0, hwreg(HW_REG_XCC_ID)" : "=s"(xcc));
  xcc &= 7;
  unsigned* claim = sync + SYNC_CLAIM;
  unsigned* modew = sync + SYNC_MODE;
  unsigned* arrive = sync + SYNC_ARRIVE;
  if (tid == 0) {
    unsigned idx = __hip_atomic_fetch_add(claim + xcc, 1u, __ATOMIC_RELAXED,
                                          __HIP_MEMORY_SCOPE_AGENT);
    // (idx>>31)==0; data-dependency forces the claim RMW to complete first
    unsigned ord = __hip_atomic_fetch_add(arrive, 1u + (idx >> 31),
                                          __ATOMIC_RELAXED,
                                          __HIP_MEMORY_SCOPE_AGENT);
    if (ord == 255u) {  // last arriver decides for everyone
      unsigned ok = 1;
#pragma unroll
      for (int i = 0; i < 8; ++i)
        ok &= (__hip_atomic_load(claim + i, __ATOMIC_RELAXED,
                                 __HIP_MEMORY_SCOPE_AGENT) == 32u);
      __hip_atomic_store(modew, ok ? 2u : 1u, __ATOMIC_RELAXED,
                         __HIP_MEMORY_SCOPE_AGENT);
    }
    unsigned mv = 0;
    int guard = 0;
    for (;;) {
      mv = __hip_atomic_load(modew, __ATOMIC_RELAXED, __HIP_MEMORY_SCOPE_AGENT);
      if (mv != 0u) break;
      if (++guard > (1 << 20)) { mv = 1u; break; }
    }
    s_bcast[0] = mv;
    s_bcast[1] = idx;
  }
  __syncthreads();
  const bool loc = (s_bcast[0] == 2u);
  const int c = loc ? (int)xcc : (blockIdx.x >> 5);
  const int wg = loc ? (int)s_bcast[1] : (blockIdx.x & 31);

  const int wcl = wg * 4 + wave;  // wave id in cluster: 0..127
  const int chbase = wcl * 4;     // this wave's 4 hidden channels
  const int m = lane & 15;        // A-fragment row id for this lane
  const int arow = (m & 3) * 512 + chbase + (m >> 2);  // i,f,g,o gate order
  unsigned short* xtw16 = (unsigned short*)xTw;
  u64* exch64 = (u64*)exch;
  unsigned* flags = sync + SYNC_FLAGS;

  // ---- one-time: weight A-fragments (hi for all; lo for Whh0/Wih1/Wih0) ----
  half8 fW0[16], fW0lo[16], fW1i[16], fW1ilo[16], fW1h[16], fX[4], fXlo[4];
  {
    const float* p0 = Whh0 + (size_t)arow * 512 + q * 8;
    const float* p1 = Wih1 + (size_t)arow * 512 + q * 8;
    const float* p2 = Whh1 + (size_t)arow * 512 + q * 8;
#pragma unroll
    for (int kt = 0; kt < 16; ++kt) {
      f32x4 a0 = *(const f32x4*)(p0 + kt * 32), b0 = *(const f32x4*)(p0 + kt * 32 + 4);
      cvt_split(a0, b0, fW0[kt], fW0lo[kt]);
      f32x4 a1 = *(const f32x4*)(p1 + kt * 32), b1 = *(const f32x4*)(p1 + kt * 32 + 4);
      cvt_split(a1, b1, fW1i[kt], fW1ilo[kt]);
      f32x4 a2 = *(const f32x4*)(p2 + kt * 32), b2 = *(const f32x4*)(p2 + kt * 32 + 4);
      half8 dummy;
      cvt_split(a2, b2, fW1h[kt], dummy);  // hi only
    }
    const float* p3 = Wih0 + (size_t)arow * 128 + q * 8;
#pragma unroll
    for (int kt = 0; kt < 4; ++kt) {
      f32x4 a3 = *(const f32x4*)(p3 + kt * 32), b3 = *(const f32x4*)(p3 + kt * 32 + 4);
      cvt_split(a3, b3, fX[kt], fXlo[kt]);
    }
  }

  float b0v[4], b1v[4];
#pragma unroll
  for (int g = 0; g < 4; ++g) {
    int rrow = g * 512 + chbase + q;
    b0v[g] = bih0[rrow] + bhh0[rrow];
    b1v[g] = bih1[rrow] + bhh1[rrow];
  }
  const int ch = chbase + q;
  const float fcw0 = fcW[ch], fcw1 = fcW[512 + ch];

  float c0 = 0.f, c1 = 0.f;
  unsigned* myflag = flags + (c * 64 + wg);
  const unsigned* spinflag = flags + (c * 64 + (lane & 31));

  const int T = 1024;
  for (int r = 0; r <= T; ++r) {
    const bool L0 = (r < T);
    const bool L1 = (r > 0);
    const bool L1h = (r > 1);

    // ---- x refresh: cluster writes ONE tau plane (tau=r&31) of window w+1.
    //      WG wg owns (b = wg>>1, d-half = wg&1); lane = d -> coalesced.
    //      Plain store in both modes (local: updates XCD L2; consumer sc0
    //      loads hit it. fallback: R4 used an agent store -> keep). ----
    if (wave == 2 && r < 992) {
      const int wnext = (r >> 5) + 1, sw = wnext % 3, rw = r & 31;
      const int xb = wg >> 1, xd = (wg & 1) * 64 + lane;
      float xv = x[((size_t)(c * 16 + xb) * 128 + xd) * 1024 + wnext * 32 + rw];
      size_t xidx = (((size_t)(sw * 8 + c) * 32 + rw) * 16 + xb) * 128 + xd;
      if (loc)
        xtw16[xidx] = f2h(xv);  // plain write-through into local L2
      else
        __hip_atomic_store(xtw16 + xidx, f2h(xv), __ATOMIC_RELAXED,
                           __HIP_MEMORY_SCOPE_AGENT);
    }

    // fallback mode: x fragments issued before the spin (latency hiding)
    half8 xf[4];
    if (!loc && L0) {
      const int s = (r >> 5) % 3, tau = r & 31;
      const u64* xp =
          (const u64*)xtw16 + (((size_t)(s * 8 + c) * 32 + tau) * 16 + bb) * 32;
#pragma unroll
      for (int kt = 0; kt < 4; ++kt) {
        u64x2 t2;
        t2.x = __hip_atomic_load(xp + kt * 8 + q * 2, __ATOMIC_RELAXED,
                                 __HIP_MEMORY_SCOPE_AGENT);
        t2.y = __hip_atomic_load(xp + kt * 8 + q * 2 + 1, __ATOMIC_RELAXED,
                                 __HIP_MEMORY_SCOPE_AGENT);
        xf[kt] = __builtin_bit_cast(half8, t2);
      }
    }

    if (r > 0) {
      // all 4 waves spin; own WG's flag is in the polled set. Tight guards:
      // a coherence failure finishes fast & wrong (diagnostic), never hangs.
      const int gmax = loc ? 2048 : (1 << 15);
      int guard = 0;
      for (;;) {
        unsigned v = loc ? ld32_sc0_wait(spinflag)
                         : __hip_atomic_load(spinflag, __ATOMIC_RELAXED,
                                             __HIP_MEMORY_SCOPE_AGENT);
        if (__ballot(v >= (unsigned)r) == ~0ull) break;
        if (++guard > gmax) break;
      }
      asm volatile("" ::: "memory");
    }

    if (loc) {
      // batch x-frag + staging loads through the local L2 (sc0), one waitcnt
      u32x4 xtmp[4], sv[8];
      if (L0) {
        const int s = (r >> 5) % 3, tau = r & 31;
        const u32x4* xp128 =
            (const u32x4*)xTw +
            ((((size_t)(s * 8 + c) * 32 + tau) * 16 + bb) * 16 + q);
#pragma unroll
        for (int kt = 0; kt < 4; ++kt) xtmp[kt] = ld128_sc0(xp128 + kt * 4);
      }
      if (r > 0) {
        const int p = (r - 1) & 1;
        const u32x4* src =
            (const u32x4*)exch + ((size_t)p * 8 + c) * 2048 + tid;
#pragma unroll
        for (int i = 0; i < 8; ++i) sv[i] = ld128_sc0(src + i * 256);
      }
      waitv0();
      if (L0) {
#pragma unroll
        for (int kt = 0; kt < 4; ++kt)
          xf[kt] = __builtin_bit_cast(half8, xtmp[kt]);
      }
      if (r > 0) {
#pragma unroll
        for (int i = 0; i < 8; ++i) {
          int f = i * 256 + tid;
          int row = f >> 6, off = f & 63;  // row = layer*16 + b (64 u32x4/row)
          *((u32x4*)(ldsbuf + row * 1040) + off) = sv[i];
        }
      }
    } else if (r > 0) {
      // fallback staging (R4): sc0+sc1 atomic u64 loads via MALL
      const int p = (r - 1) & 1;
      const u64* src = exch64 + ((size_t)p * 8 + c) * (32 * 128) + tid;
#pragma unroll
      for (int hh = 0; hh < 2; ++hh) {
        u64 v[8];
#pragma unroll
        for (int i = 0; i < 8; ++i)
          v[i] = __hip_atomic_load(src + (hh * 8 + i) * 256, __ATOMIC_RELAXED,
                                   __HIP_MEMORY_SCOPE_AGENT);
#pragma unroll
        for (int i = 0; i < 8; ++i) {
          int f = (hh * 8 + i) * 256 + tid;
          int row = f >> 7, off = f & 127;  // row = layer*16 + b
          *((u64*)(&hbuf[row >> 4][row & 15][0]) + off) = v[i];
        }
      }
    }
    __syncthreads();  // staging visible to all waves

    // ---- MFMA: L0 + L1-input chains (share h0[r-1] fragments) ----
    f32x4 accX = {b0v[0], b0v[1], b0v[2], b0v[3]};
    f32x4 a0 = {0.f, 0.f, 0.f, 0.f}, a0b = {0.f, 0.f, 0.f, 0.f};
    if (L0) {
#pragma unroll
      for (int kt = 0; kt < 4; ++kt) {
        accX = MFMA16(fX[kt], xf[kt], accX);
        accX = MFMA16(fXlo[kt], hscale(xf[kt]), accX);
      }
    }
    f32x4 a1 = {b1v[0], b1v[1], b1v[2], b1v[3]};
    f32x4 a1b = {0.f, 0.f, 0.f, 0.f}, a1c = {0.f, 0.f, 0.f, 0.f},
          a1d = {0.f, 0.f, 0.f, 0.f};
    if (L1) {
#pragma unroll
      for (int kt = 0; kt < 8; ++kt) {
        half8 hA = *(const half8*)(&hbuf[0][bb][kt * 32 + q * 8]);
        half8 hB = *(const half8*)(&hbuf[0][bb][(kt + 8) * 32 + q * 8]);
        half8 hAs = hscale(hA), hBs = hscale(hB);
        if (L0) {
          a0 = MFMA16(fW0[kt], hA, a0);
          a0b = MFMA16(fW0[kt + 8], hB, a0b);
          a0 = MFMA16(fW0lo[kt], hAs, a0);
          a0b = MFMA16(fW0lo[kt + 8], hBs, a0b);
        }
        a1 = MFMA16(fW1i[kt], hA, a1);
        a1b = MFMA16(fW1i[kt + 8], hB, a1b);
        a1 = MFMA16(fW1ilo[kt], hAs, a1);
        a1b = MFMA16(fW1ilo[kt + 8], hBs, a1b);
      }
    }

    // ---- L0 epilogue EARLY: publish h0[r] while the L1h chain runs ----
    if (L0) {
      f32x4 g0 = accX + a0 + a0b;
      float gi = sigf(g0.x), gf = sigf(g0.y), gg = tanhf_(g0.z), go = sigf(g0.w);
      c0 = gf * c0 + gi * gg;
      float h0v = go * tanhf_(c0);
      if (loc) {
        size_t idx = (((size_t)(r & 1) * 8 + c) * 32 + 0 * 16 + bb) * 512 + ch;
        exch[idx] = f2h(h0v);  // plain store into local L2
      } else {
        hout[0][bb][wave * 4 + q] = f2h(h0v);
      }
    }

    if (L1h) {
#pragma unroll
      for (int kt = 0; kt < 8; ++kt) {
        half8 hC = *(const half8*)(&hbuf[1][bb][kt * 32 + q * 8]);
        half8 hD = *(const half8*)(&hbuf[1][bb][(kt + 8) * 32 + q * 8]);
        a1c = MFMA16(fW1h[kt], hC, a1c);
        a1d = MFMA16(fW1h[kt + 8], hD, a1d);
      }
    }

    if (L1) {
      f32x4 g1 = a1 + a1b + a1c + a1d;
      float gi = sigf(g1.x), gf = sigf(g1.y), gg = tanhf_(g1.z), go = sigf(g1.w);
      c1 = gf * c1 + gi * gg;
      float h1v = go * tanhf_(c1);
      if (r == T) {
        // fc head (out zeroed by prep_kernel each call)
        float s0 = h1v * fcw0, s1 = h1v * fcw1;
        s0 += __shfl_xor(s0, 16); s0 += __shfl_xor(s0, 32);
        s1 += __shfl_xor(s1, 16); s1 += __shfl_xor(s1, 32);
        if (q == 0) {
          atomicAdd(out + (size_t)(c * 16 + bb) * 2 + 0, s0);
          atomicAdd(out + (size_t)(c * 16 + bb) * 2 + 1, s1);
        }
        if (wcl == 0 && lane < 32)
          atomicAdd(out + (size_t)(c * 16 + (lane & 15)) * 2 + (lane >> 4),
                    fcb[lane >> 4]);
      } else {
        size_t idx = (((size_t)(r & 1) * 8 + c) * 32 + 1 * 16 + bb) * 512 + ch;
        if (loc)
          exch[idx] = f2h(h1v);
        else
          hout[1][bb][wave * 4 + q] = f2h(h1v);
      }
    }
    if (r == T) break;
    __syncthreads();  // drains every wave's vmcnt -> all stores in L2/MALL
    if (loc) {
      // plain store (NO sc bits): updates the local L2 flag line in place,
      // which is exactly where the sc0 pollers read. (R5's volatile store
      // went sc0+sc1 -> around L2 to MALL -> pollers never saw it.)
      if (tid == 0)
        __hip_atomic_store(myflag, (unsigned)(r + 1), __ATOMIC_RELAXED,
                           __HIP_MEMORY_SCOPE_WORKGROUP);
    } else if (wave == 0) {
      // fallback publish (R4): wave0 coalesced u64 stores via MALL + flag
      const int p2 = r & 1;
#pragma unroll
      for (int j = 0; j < 2; ++j) {
        int f = j * 64 + lane;
        int layer = f >> 6, b_ = (f >> 2) & 15, q4 = f & 3;
        u64 v = ((const u64*)hout)[f];
        __hip_atomic_store(
            exch64 + (((size_t)p2 * 8 + c) * 32 + layer * 16 + b_) * 128 +
                wg * 4 + q4,
            v, __ATOMIC_RELAXED, __HIP_MEMORY_SCOPE_AGENT);
      }
      asm volatile("s_waitcnt vmcnt(0)" ::: "memory");
      if (lane == 0)
        __hip_atomic_store(myflag, (unsigned)(r + 1), __ATOMIC_RELAXED,
                           __HIP_MEMORY_SCOPE_AGENT);
    }
  }
}

extern "C" void kernel_launch(void* const* d_in, const int* in_sizes, int n_in,
                              void* d_out, int out_size, void* d_ws,
                              size_t ws_size, hipStream_t stream) {
  const float* x = (const float*)d_in[0];
  const float* Wih0 = (const float*)d_in[1];
  const float* Whh0 = (const float*)d_in[2];
  const float* bih0 = (const float*)d_in[3];
  const float* bhh0 = (const float*)d_in[4];
  const float* Wih1 = (const float*)d_in[5];
  const float* Whh1 = (const float*)d_in[6];
  const float* bih1 = (const float*)d_in[7];
  const float* bhh1 = (const float*)d_in[8];
  const float* fcW = (const float*)d_in[9];
  const float* fcb = (const float*)d_in[10];

  char* ws = (char*)d_ws;  // uses < 4MB total
  unsigned* sync = (unsigned*)ws;
  unsigned short* exch = (unsigned short*)(ws + WS_EXCH_OFF);
  _Float16* xTw = (_Float16*)(ws + WS_XTW_OFF);
  float* out = (float*)d_out;

  prep_kernel<<<dim3(128), dim3(256), 0, stream>>>(x, xTw, sync, out);
  lstm_scan<<<dim3(256), dim3(256), 0, stream>>>(Whh0, bih0, bhh0, Wih1, Whh1,
                                                 bih1, bhh1, fcW, fcb, Wih0, x,
                                                 sync, exch, xTw, out);
}

// Round 7
// 4115.004 us; speedup vs baseline: 46.0386x; 46.0386x over previous
//
#include <hip/hip_runtime.h>
#include <hip/hip_fp16.h>

// ============================================================================
// LSTM_78176994722094: 2-layer LSTM (B=128, D_IN=128, T=1024, H=512) + fc head.
//
// Round 7. R6 forensics: plain stores DO reach the XCD L2 (write-through L1),
// but sc0-only loads PROBE L1 (sc bits = scope encoding, not bypass) -> the
// constantly-polled flag line sat stale in L1 -> every spin exited via guard
// (189ms = 1024 x 2048-poll guard), data mostly fresh only because 32KB/round
// staging thrashed the 32KB L1 (absmax 4.88e-4 drift).
//
// R7: XCD-local exchange with PROVEN load encodings. In local mode, all
// exchange/flag/xTw STORES are plain (dirty line in the local L2); all
// cross-WG LOADS stay agent-scope (sc0 sc1 -- bypass L1; bet: they probe and
// hit dirty local-L2 lines, the architecturally-sane behavior). Everything
// else is byte-equivalent to the R4 path (6.67ms, correct): same u64 agent
// staging loads, same spin, same LDS layout. Fallback mode (unbalanced
// placement) IS R4. Plus: x-refresh batched float4 every 4th round (16x ->
// 4x line amplification), spin guard 512 (fast diagnostic fail, no hang).
//
// Design: persistent kernel, 8 clusters x 32 WGs (256 blocks, 1/CU, 4 waves).
// Startup: blocks read HW_REG_XCC_ID, claim slots; last arriver publishes
// mode (balanced 32/XCD -> local: cluster = XCD). Cluster c owns batch rows
// [16c,16c+16). Each wave holds 16 rows of each matrix as MFMA A-fragments in
// VGPRs, split-precision (hi fp16 + 2^-11*lo fp16 on Whh0/Wih1/Wih0; absmax
// 1.22e-4). Layer 1 skewed one step behind layer 0 -> ONE flag barrier/round:
//   round r: compute h0[r] (L0) and h1[r-1] (L1) from h0[r-1], h1[r-2].
//
// Workspace (<4MB):
//   [0, 2KB)           flags: u32 per (cluster,wg), 64-u32 stride per cluster
//   [4KB, 4.5KB)       claim[8] / mode / arrive (startup handshake)
//   [64KB, 576KB)      h exchange: [parity2][cluster8][layer2][b16][ch512] fp16
//   [640KB, 640KB+3MB) xTw: [slot3][cluster8][tau32][b16][d128] fp16
// ============================================================================

typedef _Float16 half8 __attribute__((ext_vector_type(8)));
typedef float f32x4 __attribute__((ext_vector_type(4)));
typedef unsigned long long u64;
typedef u64 u64x2 __attribute__((ext_vector_type(2)));

#define MFMA16(a, b, c) __builtin_amdgcn_mfma_f32_16x16x32_f16((a), (b), (c), 0, 0, 0)

#define WS_EXCH_OFF (64 << 10)
#define WS_XTW_OFF (640 << 10)
// sync word indices (u32) within ws base
#define SYNC_FLAGS 0      // 8 clusters x 64 u32
#define SYNC_CLAIM 1024   // 8 u32
#define SYNC_MODE 1040    // 1 u32 (0=undecided, 1=fallback, 2=local)
#define SYNC_ARRIVE 1056  // 1 u32

__device__ __forceinline__ float sigf(float x) {
  return __builtin_amdgcn_rcpf(1.f + exp2f(-1.44269504f * x));
}
__device__ __forceinline__ float tanhf_(float x) {
  return 1.f - 2.f * __builtin_amdgcn_rcpf(1.f + exp2f(2.88539008f * x));
}
__device__ __forceinline__ unsigned short f2h(float x) {
  _Float16 h = (_Float16)x;  // RNE
  unsigned short b;
  __builtin_memcpy(&b, &h, 2);
  return b;
}

// split 8 fp32 weights -> hi fp16 + lo fp16 (lo = (w - hi) * 2^11)
__device__ __forceinline__ void cvt_split(const f32x4& a, const f32x4& b,
                                          half8& hi, half8& lo) {
#pragma unroll
  for (int i = 0; i < 4; ++i) {
    float w0 = a[i], w1 = b[i];
    _Float16 h0 = (_Float16)w0, h1 = (_Float16)w1;
    hi[i] = h0;
    hi[i + 4] = h1;
    lo[i] = (_Float16)((w0 - (float)h0) * 2048.0f);
    lo[i + 4] = (_Float16)((w1 - (float)h1) * 2048.0f);
  }
}
// scale a fragment by 2^-11 (exact exponent shift; v_pk_mul_f16)
__device__ __forceinline__ half8 hscale(half8 v) {
  half8 r;
#pragma unroll
  for (int i = 0; i < 8; ++i) r[i] = v[i] * (_Float16)4.8828125e-4f;
  return r;
}

// ---------------------------------------------------------------------------
// Prepass: fill xTw window 0 (t=0..31) slot 0, zero sync area (16KB) and out.
// ---------------------------------------------------------------------------
__global__ void __launch_bounds__(256) prep_kernel(const float* __restrict__ x,
                                                   _Float16* __restrict__ xTw,
                                                   unsigned* __restrict__ sync,
                                                   float* __restrict__ out) {
  const int bid = blockIdx.x;  // 128 = 8c * 16b
  const int c = bid >> 4, b16 = bid & 15;
  const int tid = threadIdx.x;
  if (bid == 0) {
#pragma unroll
    for (int i = 0; i < 16; ++i) sync[i * 256 + tid] = 0;  // 16KB sync area
    out[tid] = 0.f;  // out_size = B*OUT = 256
  }
  const int d = tid & 127, th = tid >> 7;  // th: tau half (0/1)
  const float* src = x + ((size_t)(c * 16 + b16) * 128 + d) * 1024 + th * 16;
  _Float16* dst = xTw + ((size_t)c * 32 + th * 16) * (16 * 128) + b16 * 128 + d;
#pragma unroll
  for (int i = 0; i < 16; ++i) dst[(size_t)i * (16 * 128)] = (_Float16)src[i];
}

// ---------------------------------------------------------------------------
// Persistent scan kernel. MFMA 16x16x32 f16 layouts (verified R1-R6):
//   A[m=lane&15][k=(lane>>4)*8+j], B[k][n=lane&15], D[m=(lane>>4)*4+reg][n].
// ---------------------------------------------------------------------------
__global__ void __launch_bounds__(256, 1) lstm_scan(
    const float* __restrict__ Whh0, const float* __restrict__ bih0,
    const float* __restrict__ bhh0, const float* __restrict__ Wih1,
    const float* __restrict__ Whh1, const float* __restrict__ bih1,
    const float* __restrict__ bhh1, const float* __restrict__ fcW,
    const float* __restrict__ fcb, const float* __restrict__ Wih0,
    const float* __restrict__ x, unsigned* __restrict__ sync,
    unsigned short* __restrict__ exch, _Float16* __restrict__ xTw,
    float* __restrict__ out) {
  __shared__ __align__(16) _Float16 hbuf[2][16][520];
  __shared__ __align__(16) unsigned short hout[2][16][16];  // fallback only
  __shared__ unsigned s_bcast[2];

  const int tid = threadIdx.x;
  const int wave = tid >> 6;
  const int lane = tid & 63;
  const int q = lane >> 4;
  const int bb = lane & 15;

  // ---- startup: XCD discovery + slot claim + grid barrier + mode decide ----
  unsigned xcc;
  asm("s_getreg_b32 %0, hwreg(HW_REG_XCC_ID)" : "=s"(xcc));
  xcc &= 7;
  unsigned* claim = sync + SYNC_CLAIM;
  unsigned* modew = sync + SYNC_MODE;
  unsigned* arrive = sync + SYNC_ARRIVE;
  if (tid == 0) {
    unsigned idx = __hip_atomic_fetch_add(claim + xcc, 1u, __ATOMIC_RELAXED,
                                          __HIP_MEMORY_SCOPE_AGENT);
    // (idx>>31)==0; data-dependency forces the claim RMW to complete first
    unsigned ord = __hip_atomic_fetch_add(arrive, 1u + (idx >> 31),
                                          __ATOMIC_RELAXED,
                                          __HIP_MEMORY_SCOPE_AGENT);
    if (ord == 255u) {  // last arriver decides for everyone
      unsigned ok = 1;
#pragma unroll
      for (int i = 0; i < 8; ++i)
        ok &= (__hip_atomic_load(claim + i, __ATOMIC_RELAXED,
                                 __HIP_MEMORY_SCOPE_AGENT) == 32u);
      __hip_atomic_store(modew, ok ? 2u : 1u, __ATOMIC_RELAXED,
                         __HIP_MEMORY_SCOPE_AGENT);
    }
    unsigned mv = 0;
    int guard = 0;
    for (;;) {
      mv = __hip_atomic_load(modew, __ATOMIC_RELAXED, __HIP_MEMORY_SCOPE_AGENT);
      if (mv != 0u) break;
      if (++guard > (1 << 18)) { mv = 1u; break; }
    }
    s_bcast[0] = mv;
    s_bcast[1] = idx;
  }
  __syncthreads();
  const bool loc = (s_bcast[0] == 2u);
  const int c = loc ? (int)xcc : (blockIdx.x >> 5);
  const int wg = loc ? (int)s_bcast[1] : (blockIdx.x & 31);

  const int wcl = wg * 4 + wave;  // wave id in cluster: 0..127
  const int chbase = wcl * 4;     // this wave's 4 hidden channels
  const int m = lane & 15;        // A-fragment row id for this lane
  const int arow = (m & 3) * 512 + chbase + (m >> 2);  // i,f,g,o gate order
  unsigned short* xtw16 = (unsigned short*)xTw;
  u64* exch64 = (u64*)exch;
  unsigned* flags = sync + SYNC_FLAGS;

  // ---- one-time: weight A-fragments (hi for all; lo for Whh0/Wih1/Wih0) ----
  half8 fW0[16], fW0lo[16], fW1i[16], fW1ilo[16], fW1h[16], fX[4], fXlo[4];
  {
    const float* p0 = Whh0 + (size_t)arow * 512 + q * 8;
    const float* p1 = Wih1 + (size_t)arow * 512 + q * 8;
    const float* p2 = Whh1 + (size_t)arow * 512 + q * 8;
#pragma unroll
    for (int kt = 0; kt < 16; ++kt) {
      f32x4 a0 = *(const f32x4*)(p0 + kt * 32), b0 = *(const f32x4*)(p0 + kt * 32 + 4);
      cvt_split(a0, b0, fW0[kt], fW0lo[kt]);
      f32x4 a1 = *(const f32x4*)(p1 + kt * 32), b1 = *(const f32x4*)(p1 + kt * 32 + 4);
      cvt_split(a1, b1, fW1i[kt], fW1ilo[kt]);
      f32x4 a2 = *(const f32x4*)(p2 + kt * 32), b2 = *(const f32x4*)(p2 + kt * 32 + 4);
      half8 dummy;
      cvt_split(a2, b2, fW1h[kt], dummy);  // hi only
    }
    const float* p3 = Wih0 + (size_t)arow * 128 + q * 8;
#pragma unroll
    for (int kt = 0; kt < 4; ++kt) {
      f32x4 a3 = *(const f32x4*)(p3 + kt * 32), b3 = *(const f32x4*)(p3 + kt * 32 + 4);
      cvt_split(a3, b3, fX[kt], fXlo[kt]);
    }
  }

  float b0v[4], b1v[4];
#pragma unroll
  for (int g = 0; g < 4; ++g) {
    int rrow = g * 512 + chbase + q;
    b0v[g] = bih0[rrow] + bhh0[rrow];
    b1v[g] = bih1[rrow] + bhh1[rrow];
  }
  const int ch = chbase + q;
  const float fcw0 = fcW[ch], fcw1 = fcW[512 + ch];

  float c0 = 0.f, c1 = 0.f;
  unsigned* myflag = flags + (c * 64 + wg);
  const unsigned* spinflag = flags + (c * 64 + (lane & 31));

  const int T = 1024;
  for (int r = 0; r <= T; ++r) {
    const bool L0 = (r < T);
    const bool L1 = (r > 0);
    const bool L1h = (r > 1);

    // ---- x refresh: every 4th round wave 2 loads a float4 (4 taus) per lane
    //      and writes 4 tau planes of window w+1 (lane = d -> coalesced).
    //      float4 read cuts HBM line amplification 16x -> 4x. ----
    if (wave == 2 && r < 992 && (r & 3) == 0) {
      const int wnext = (r >> 5) + 1, sw = wnext % 3, rw = r & 31;
      const int xb = wg >> 1, xd = (wg & 1) * 64 + lane;
      f32x4 xv4 = *(const f32x4*)(x + ((size_t)(c * 16 + xb) * 128 + xd) * 1024 +
                                  wnext * 32 + rw);
#pragma unroll
      for (int j = 0; j < 4; ++j) {
        size_t xidx =
            (((size_t)(sw * 8 + c) * 32 + rw + j) * 16 + xb) * 128 + xd;
        if (loc)
          xtw16[xidx] = f2h(xv4[j]);  // plain -> dirty line in local L2
        else
          __hip_atomic_store(xtw16 + xidx, f2h(xv4[j]), __ATOMIC_RELAXED,
                             __HIP_MEMORY_SCOPE_AGENT);
      }
    }

    // x fragments for t=r (agent u64 loads, issued before the spin; the slot
    // was fully written >=32 rounds ago -> drained to L2/MALL)
    half8 xf[4];
    if (L0) {
      const int s = (r >> 5) % 3, tau = r & 31;
      const u64* xp =
          (const u64*)xtw16 + (((size_t)(s * 8 + c) * 32 + tau) * 16 + bb) * 32;
#pragma unroll
      for (int kt = 0; kt < 4; ++kt) {
        u64x2 t2;
        t2.x = __hip_atomic_load(xp + kt * 8 + q * 2, __ATOMIC_RELAXED,
                                 __HIP_MEMORY_SCOPE_AGENT);
        t2.y = __hip_atomic_load(xp + kt * 8 + q * 2 + 1, __ATOMIC_RELAXED,
                                 __HIP_MEMORY_SCOPE_AGENT);
        xf[kt] = __builtin_bit_cast(half8, t2);
      }
    }

    if (r > 0) {
      // all 4 waves spin with AGENT loads (bypass L1; local mode: probe-hit
      // the dirty flag line in the XCD L2). Guard 512: a coherence failure
      // finishes fast & wrong (diagnostic), never hangs.
      int guard = 0;
      for (;;) {
        unsigned v = __hip_atomic_load(spinflag, __ATOMIC_RELAXED,
                                       __HIP_MEMORY_SCOPE_AGENT);
        if (__ballot(v >= (unsigned)r) == ~0ull) break;
        if (++guard > 512) break;
      }
      asm volatile("" ::: "memory");  // keep staging loads below the spin
      // stage h0[r-1], h1[r-2] (32KB) into padded LDS rows (agent u64 loads;
      // local mode: these hit the dirty exchange lines in the local L2)
      const int p = (r - 1) & 1;
      const u64* src = exch64 + ((size_t)p * 8 + c) * (32 * 128) + tid;
#pragma unroll
      for (int hh = 0; hh < 2; ++hh) {
        u64 v[8];
#pragma unroll
        for (int i = 0; i < 8; ++i)
          v[i] = __hip_atomic_load(src + (hh * 8 + i) * 256, __ATOMIC_RELAXED,
                                   __HIP_MEMORY_SCOPE_AGENT);
#pragma unroll
        for (int i = 0; i < 8; ++i) {
          int f = (hh * 8 + i) * 256 + tid;
          int row = f >> 7, off = f & 127;  // row = layer*16 + b
          *((u64*)(&hbuf[row >> 4][row & 15][0]) + off) = v[i];
        }
      }
    }
    __syncthreads();  // staging visible to all waves

    // ---- MFMA: L0 + L1-input chains (share h0[r-1] fragments) ----
    f32x4 accX = {b0v[0], b0v[1], b0v[2], b0v[3]};
    f32x4 a0 = {0.f, 0.f, 0.f, 0.f}, a0b = {0.f, 0.f, 0.f, 0.f};
    if (L0) {
#pragma unroll
      for (int kt = 0; kt < 4; ++kt) {
        accX = MFMA16(fX[kt], xf[kt], accX);
        accX = MFMA16(fXlo[kt], hscale(xf[kt]), accX);
      }
    }
    f32x4 a1 = {b1v[0], b1v[1], b1v[2], b1v[3]};
    f32x4 a1b = {0.f, 0.f, 0.f, 0.f}, a1c = {0.f, 0.f, 0.f, 0.f},
          a1d = {0.f, 0.f, 0.f, 0.f};
    if (L1) {
#pragma unroll
      for (int kt = 0; kt < 8; ++kt) {
        half8 hA = *(const half8*)(&hbuf[0][bb][kt * 32 + q * 8]);
        half8 hB = *(const half8*)(&hbuf[0][bb][(kt + 8) * 32 + q * 8]);
        half8 hAs = hscale(hA), hBs = hscale(hB);
        if (L0) {
          a0 = MFMA16(fW0[kt], hA, a0);
          a0b = MFMA16(fW0[kt + 8], hB, a0b);
          a0 = MFMA16(fW0lo[kt], hAs, a0);
          a0b = MFMA16(fW0lo[kt + 8], hBs, a0b);
        }
        a1 = MFMA16(fW1i[kt], hA, a1);
        a1b = MFMA16(fW1i[kt + 8], hB, a1b);
        a1 = MFMA16(fW1ilo[kt], hAs, a1);
        a1b = MFMA16(fW1ilo[kt + 8], hBs, a1b);
      }
    }

    // ---- L0 epilogue EARLY: publish h0[r] while the L1h chain runs ----
    if (L0) {
      f32x4 g0 = accX + a0 + a0b;
      float gi = sigf(g0.x), gf = sigf(g0.y), gg = tanhf_(g0.z), go = sigf(g0.w);
      c0 = gf * c0 + gi * gg;
      float h0v = go * tanhf_(c0);
      if (loc) {
        size_t idx = (((size_t)(r & 1) * 8 + c) * 32 + 0 * 16 + bb) * 512 + ch;
        exch[idx] = f2h(h0v);  // plain -> dirty in local L2
      } else {
        hout[0][bb][wave * 4 + q] = f2h(h0v);
      }
    }

    if (L1h) {
#pragma unroll
      for (int kt = 0; kt < 8; ++kt) {
        half8 hC = *(const half8*)(&hbuf[1][bb][kt * 32 + q * 8]);
        half8 hD = *(const half8*)(&hbuf[1][bb][(kt + 8) * 32 + q * 8]);
        a1c = MFMA16(fW1h[kt], hC, a1c);
        a1d = MFMA16(fW1h[kt + 8], hD, a1d);
      }
    }

    if (L1) {
      f32x4 g1 = a1 + a1b + a1c + a1d;
      float gi = sigf(g1.x), gf = sigf(g1.y), gg = tanhf_(g1.z), go = sigf(g1.w);
      c1 = gf * c1 + gi * gg;
      float h1v = go * tanhf_(c1);
      if (r == T) {
        // fc head (out zeroed by prep_kernel each call)
        float s0 = h1v * fcw0, s1 = h1v * fcw1;
        s0 += __shfl_xor(s0, 16); s0 += __shfl_xor(s0, 32);
        s1 += __shfl_xor(s1, 16); s1 += __shfl_xor(s1, 32);
        if (q == 0) {
          atomicAdd(out + (size_t)(c * 16 + bb) * 2 + 0, s0);
          atomicAdd(out + (size_t)(c * 16 + bb) * 2 + 1, s1);
        }
        if (wcl == 0 && lane < 32)
          atomicAdd(out + (size_t)(c * 16 + (lane & 15)) * 2 + (lane >> 4),
                    fcb[lane >> 4]);
      } else {
        size_t idx = (((size_t)(r & 1) * 8 + c) * 32 + 1 * 16 + bb) * 512 + ch;
        if (loc)
          exch[idx] = f2h(h1v);
        else
          hout[1][bb][wave * 4 + q] = f2h(h1v);
      }
    }
    if (r == T) break;
    __syncthreads();  // each wave waits own vmcnt before s_barrier -> ALL
                      // waves' plain/agent stores drained (to L2 / MALL)
    if (loc) {
      // plain flag store -> dirty line in local L2; agent-load pollers
      // bypass L1 and probe-hit it there.
      if (tid == 0)
        __hip_atomic_store(myflag, (unsigned)(r + 1), __ATOMIC_RELAXED,
                           __HIP_MEMORY_SCOPE_WORKGROUP);
    } else if (wave == 0) {
      // fallback publish (R4): wave0 coalesced u64 stores via MALL + flag
      const int p2 = r & 1;
#pragma unroll
      for (int j = 0; j < 2; ++j) {
        int f = j * 64 + lane;
        int layer = f >> 6, b_ = (f >> 2) & 15, q4 = f & 3;
        u64 v = ((const u64*)hout)[f];
        __hip_atomic_store(
            exch64 + (((size_t)p2 * 8 + c) * 32 + layer * 16 + b_) * 128 +
                wg * 4 + q4,
            v, __ATOMIC_RELAXED, __HIP_MEMORY_SCOPE_AGENT);
      }
      asm volatile("s_waitcnt vmcnt(0)" ::: "memory");
      if (lane == 0)
        __hip_atomic_store(myflag, (unsigned)(r + 1), __ATOMIC_RELAXED,
                           __HIP_MEMORY_SCOPE_AGENT);
    }
  }
}

extern "C" void kernel_launch(void* const* d_in, const int* in_sizes, int n_in,
                              void* d_out, int out_size, void* d_ws,
                              size_t ws_size, hipStream_t stream) {
  const float* x = (const float*)d_in[0];
  const float* Wih0 = (const float*)d_in[1];
  const float* Whh0 = (const float*)d_in[2];
  const float* bih0 = (const float*)d_in[3];
  const float* bhh0 = (const float*)d_in[4];
  const float* Wih1 = (const float*)d_in[5];
  const float* Whh1 = (const float*)d_in[6];
  const float* bih1 = (const float*)d_in[7];
  const float* bhh1 = (const float*)d_in[8];
  const float* fcW = (const float*)d_in[9];
  const float* fcb = (const float*)d_in[10];

  char* ws = (char*)d_ws;  // uses < 4MB total
  unsigned* sync = (unsigned*)ws;
  unsigned short* exch = (unsigned short*)(ws + WS_EXCH_OFF);
  _Float16* xTw = (_Float16*)(ws + WS_XTW_OFF);
  float* out = (float*)d_out;

  prep_kernel<<<dim3(128), dim3(256), 0, stream>>>(x, xTw, sync, out);
  lstm_scan<<<dim3(256), dim3(256), 0, stream>>>(Whh0, bih0, bhh0, Wih1, Whh1,
                                                 bih1, bhh1, fcW, fcb, Wih0, x,
                                                 sync, exch, xTw, out);
}